// Round 11
// baseline (524.113 us; speedup 1.0000x reference)
//
#include <hip/hip_runtime.h>
#include <math.h>

#define N_PTS 8192
#define B_SZ 4
#define SEED_NUM 409
#define FPS_THREADS 256  // 4 waves, 1 per SIMD
#define LTOT 653  // 65+98+131+163+196

typedef float f2 __attribute__((ext_vector_type(2)));
typedef float f4 __attribute__((ext_vector_type(4)));

// Exact IEEE f32 squared distance, same op order as the reference:
// ((dx*dx + dy*dy) + dz*dz), no FMA contraction.
__device__ __forceinline__ float sqdist(float ax, float ay, float az,
                                        float bx, float by, float bz) {
  float dx = __fsub_rn(ax, bx);
  float dy = __fsub_rn(ay, by);
  float dz = __fsub_rn(az, bz);
  return __fadd_rn(__fadd_rn(__fmul_rn(dx, dx), __fmul_rn(dy, dy)),
                   __fmul_rn(dz, dz));
}

#define FOR16(M) \
  M(0) M(1) M(2) M(3) M(4) M(5) M(6) M(7) \
  M(8) M(9) M(10) M(11) M(12) M(13) M(14) M(15)
#define FOR16_REV(M) \
  M(15) M(14) M(13) M(12) M(11) M(10) M(9) M(8) \
  M(7) M(6) M(5) M(4) M(3) M(2) M(1) M(0)

// --- single-instruction-per-stage DPP reduces (ctrl seq validated R6-R10) ---
template <int CTRL, int RM, bool BC>
__device__ __forceinline__ float dpp_mov_f(float x, float old) {
  return __int_as_float(__builtin_amdgcn_update_dpp(
      __float_as_int(old), __float_as_int(x), CTRL, RM, 0xf, BC));
}
// wave max of non-negative f32; result valid in lane 63.
__device__ __forceinline__ float wave_max_f32(float x) {
  x = fmaxf(x, dpp_mov_f<0x111, 0xf, true>(x, 0.0f));   // row_shr:1 (OOB->0)
  x = fmaxf(x, dpp_mov_f<0x112, 0xf, true>(x, 0.0f));   // row_shr:2
  x = fmaxf(x, dpp_mov_f<0x114, 0xf, true>(x, 0.0f));   // row_shr:4
  x = fmaxf(x, dpp_mov_f<0x118, 0xf, true>(x, 0.0f));   // row_shr:8
  x = fmaxf(x, dpp_mov_f<0x142, 0xa, false>(x, x));     // row_bcast:15
  x = fmaxf(x, dpp_mov_f<0x143, 0xc, false>(x, x));     // row_bcast:31
  return x;
}
template <int CTRL, int RM>
__device__ __forceinline__ unsigned dpp_mov_u_keep(unsigned x) {
  return (unsigned)__builtin_amdgcn_update_dpp((int)x, (int)x, CTRL, RM, 0xf,
                                               false);  // OOB keeps self
}
// wave min of u32; result valid in lane 63.
__device__ __forceinline__ unsigned wave_min_u32(unsigned x) {
  unsigned t;
  t = dpp_mov_u_keep<0x111, 0xf>(x); x = t < x ? t : x;
  t = dpp_mov_u_keep<0x112, 0xf>(x); x = t < x ? t : x;
  t = dpp_mov_u_keep<0x114, 0xf>(x); x = t < x ? t : x;
  t = dpp_mov_u_keep<0x118, 0xf>(x); x = t < x ? t : x;
  t = dpp_mov_u_keep<0x142, 0xa>(x); x = t < x ? t : x;
  t = dpp_mov_u_keep<0x143, 0xc>(x); x = t < x ? t : x;
  return x;
}

// ---------------------------------------------------------------------------
// Kernel 1: farthest point sampling. One block per batch, 4 waves (1/SIMD).
// R10 counters: ~68% VALU-busy on active CUs, ~650 instr/wave/step -> the f2
// chain was SCALARIZED (extracting m.x/m.y for argmax tracking defeats pk
// lowering) and the u64 DPP reduce costs 5 instr/stage. R11 restructure:
// (1) main loop is pure f2 ops (sub/mul/add/min/max accumulate, no extracts)
//     so it can lower to v_pk_*;
// (2) wave f32-max reduce, 1 instr/stage (mov_dpp fused into v_max_f32),
//     readlane(63) -> SGPR broadcast;
// (3) index pass: descending overwrite of a pair-code (inline consts 0..31)
//     where md == wave max, abs idx = code*256+tid, wave u32-min reduce
//     (1 instr/stage); lane 63 packs (wmax_bits<<32)|(8191-idx) per wave.
// Cross-wave: 4-key u64 max scan post-barrier (value desc, then min index)
// == exact jnp.argmax semantics (wave max is bitwise one of the inputs).
// ---------------------------------------------------------------------------
__global__ __launch_bounds__(FPS_THREADS, 1) void fps_kernel(
    const float* __restrict__ pcs, float* __restrict__ seeds,
    double* __restrict__ sums /*25 doubles*/) {
#pragma clang fp contract(off)
  const int b = blockIdx.x;
  const int tid = threadIdx.x;
  const int lane = tid & 63, wid = tid >> 6;  // 4 waves
  const float* base = pcs + (size_t)b * N_PTS * 3;

  if (b == 0 && tid < 25) sums[tid] = 0.0;  // zero totS[5]+accA[20]

  __shared__ f4 spts4[N_PTS];              // 128 KiB: winner-coord broadcast
  __shared__ float seedbuf[SEED_NUM * 3];  // 4.8 KiB: deferred seed output
  __shared__ unsigned long long red[2][4];

  // pair j holds points i0 = tid + (2j)*256 and i1 = tid + (2j+1)*256
#define FPS_DECL(j) f2 px##j, py##j, pz##j, md##j;
  FOR16(FPS_DECL)
#undef FPS_DECL

#define FPS_INIT(j)                                   \
  {                                                   \
    const int i0 = tid + (2 * (j)) * FPS_THREADS;     \
    const int i1 = i0 + FPS_THREADS;                  \
    px##j = (f2){base[i0 * 3 + 0], base[i1 * 3 + 0]}; \
    py##j = (f2){base[i0 * 3 + 1], base[i1 * 3 + 1]}; \
    pz##j = (f2){base[i0 * 3 + 2], base[i1 * 3 + 2]}; \
    md##j = (f2){1e10f, 1e10f}; /* ref 1e10 exact */  \
    spts4[i0] = (f4){px##j.x, py##j.x, pz##j.x, 0.f}; \
    spts4[i1] = (f4){px##j.y, py##j.y, pz##j.y, 0.f}; \
  }
  FOR16(FPS_INIT)
#undef FPS_INIT

  // Pin coords in VGPRs (asm results can't be rematerialized from memory).
#define FPS_PIN(j) asm volatile("" : "+v"(px##j), "+v"(py##j), "+v"(pz##j));
  FOR16(FPS_PIN)
#undef FPS_PIN

  float cx = base[0], cy = base[1], cz = base[2];

  for (int s = 0; s < SEED_NUM; ++s) {
    if (tid == 0) {
      seedbuf[s * 3 + 0] = cx;
      seedbuf[s * 3 + 1] = cy;
      seedbuf[s * 3 + 2] = cz;
    }
    const f2 ccx = (f2){cx, cx}, ccy = (f2){cy, cy}, ccz = (f2){cz, cz};
    f2 mx = (f2){-1.0f, -1.0f};
    // ---- distance + min update + packed max accumulate (NO extracts) ----
#define FPS_UPD(j)                                     \
  {                                                    \
    const f2 dx = px##j - ccx;                         \
    const f2 dy = py##j - ccy;                         \
    const f2 dz = pz##j - ccz;                         \
    const f2 t0 = dx * dx;                             \
    const f2 t1 = dy * dy;                             \
    const f2 t2 = dz * dz;                             \
    const f2 d2 = (t0 + t1) + t2;                      \
    const f2 m = __builtin_elementwise_min(md##j, d2); \
    md##j = m;                                         \
    mx = __builtin_elementwise_max(mx, m);             \
  }
    FOR16(FPS_UPD)
#undef FPS_UPD
    // ---- wave value-max (1 instr/stage DPP), broadcast via readlane ----
    const float bv = fmaxf(mx.x, mx.y);
    const float wmax_l63 = wave_max_f32(bv);
    const float s_wmax =
        __int_as_float(__builtin_amdgcn_readlane(__float_as_int(wmax_l63), 63));
    // ---- index pass: descending overwrite with inline-const pair codes ----
    unsigned lc = 64;  // sentinel (> any valid code 0..31)
#define FPS_IDX(j)                                                \
  lc = (md##j.y == s_wmax) ? (unsigned)(2 * (j) + 1) : lc;        \
  lc = (md##j.x == s_wmax) ? (unsigned)(2 * (j)) : lc;
    FOR16_REV(FPS_IDX)
#undef FPS_IDX
    const unsigned li = (lc << 8) + (unsigned)tid;  // absolute index
    const unsigned wmin_l63 = wave_min_u32(li);
    const unsigned s_wmin =
        (unsigned)__builtin_amdgcn_readlane((int)wmin_l63, 63);
    // per-wave packed key: value desc, then min index (matches jnp.argmax)
    if (lane == 63) {
      red[s & 1][wid] =
          ((unsigned long long)__float_as_uint(s_wmax) << 32) |
          (unsigned long long)(unsigned)(N_PTS - 1 - s_wmin);
    }
    __syncthreads();
    const unsigned long long* rr = red[s & 1];
    unsigned long long kmax = rr[0];
#pragma unroll
    for (int w = 1; w < 4; ++w) {
      const unsigned long long t = rr[w];
      kmax = (t > kmax) ? t : kmax;
    }
    const int ci = N_PTS - 1 - (int)(unsigned)(kmax & 0xffffull);
    const f4 c = spts4[ci];  // one ds_read_b128, same-address broadcast
    cx = c.x;
    cy = c.y;
    cz = c.z;
  }

  // bulk seed writeback (ordered by the final in-loop barrier)
  __syncthreads();
  float* sg = seeds + (size_t)b * SEED_NUM * 3;
  for (int i = tid; i < SEED_NUM * 3; i += FPS_THREADS) sg[i] = seedbuf[i];
}

// ---------------------------------------------------------------------------
// Kernel 2: one block per group, ALL 5 percentages at once (unchanged —
// est. ~30-40 us). Order-free atomic-append collection (valid-sets nest, KNN
// is set-order-independent); ordered-recompaction fallback for the
// measure-zero cnt>K case; 4-thread/row two-min KNN with shfl_xor merge.
// ---------------------------------------------------------------------------
__global__ __launch_bounds__(256) void group_kernel(
    const float* __restrict__ pcs, const float* __restrict__ seeds,
    double* __restrict__ totS /*[5]*/, double* __restrict__ accA /*[5][4]*/) {
  const int g = blockIdx.x;  // 0 .. B*SEED_NUM-1
  const int b = g / SEED_NUM;
  const int tid = threadIdx.x;
  const int lane = tid & 63, wid = tid >> 6;

  const int Kc[5] = {65, 98, 131, 163, 196};
  const int off[5] = {0, 65, 163, 294, 457};
  const double Pd[5] = {0.004, 0.006, 0.008, 0.01, 0.012};
  float r2c[5], expnf[5], expdc[5];
#pragma unroll
  for (int p = 0; p < 5; ++p) {
    const double pd = Pd[p];
    const double rd = sqrt(pd);
    r2c[p] = (float)(rd * rd);                     // weak f32 cast of r*r
    const double expn_d = 8192.0 * pd;
    expnf[p] = (float)expn_d;
    expdc[p] = sqrtf((float)(M_PI / expn_d * pd));  // expect_dis (= sqrt(pi/N))
  }

  const float* base = pcs + (size_t)b * N_PTS * 3;
  const float* sp = seeds + (size_t)g * 3;
  const float sx = sp[0], sy = sp[1], sz = sp[2];

  __shared__ float lx[LTOT], ly[LTOT], lz[LTOT];
  __shared__ int cnt[5];
  __shared__ int wtot[4];     // fallback path only
  __shared__ double wsum[4];

  if (tid < 5) cnt[tid] = 0;
  __syncthreads();

  // ---- single barrier-free scan: d2 once, append to each nested list ----
  const float r2max = r2c[4];
  for (int i = tid; i < N_PTS; i += 256) {
    const float x = base[i * 3 + 0];
    const float y = base[i * 3 + 1];
    const float z = base[i * 3 + 2];
    const float d2 = sqdist(x, y, z, sx, sy, sz);
    if (d2 < r2max) {
#pragma unroll
      for (int p = 0; p < 5; ++p) {
        if (d2 < r2c[p]) {
          const int pos = atomicAdd(&cnt[p], 1);
          if (pos < Kc[p]) {
            lx[off[p] + pos] = x;
            ly[off[p] + pos] = y;
            lz[off[p] + pos] = z;
          }
        }
      }
    }
  }
  __syncthreads();

  // ---- rare fallback: cnt>K needs the K smallest indices (ordered) ----
#pragma unroll
  for (int p = 0; p < 5; ++p) {
    if (cnt[p] > Kc[p]) {  // block-uniform (LDS value, post-barrier)
      int run = 0;
      for (int base_i = 0; base_i < N_PTS; base_i += 256) {
        const int i = base_i + tid;
        const float x = base[i * 3 + 0];
        const float y = base[i * 3 + 1];
        const float z = base[i * 3 + 2];
        const float d2 = sqdist(x, y, z, sx, sy, sz);
        const bool valid = d2 < r2c[p];
        const unsigned long long m = __ballot(valid);
        if (lane == 0) wtot[wid] = __popcll(m);
        __syncthreads();
        int pos = run + __popcll(m & ((1ull << lane) - 1ull));
        for (int w = 0; w < wid; ++w) pos += wtot[w];
        if (valid && pos < Kc[p]) {
          lx[off[p] + pos] = x; ly[off[p] + pos] = y; lz[off[p] + pos] = z;
        }
        run += wtot[0] + wtot[1] + wtot[2] + wtot[3];
        __syncthreads();
      }
    }
  }

  // ---- KNN + clutter per percentage: 4 threads/row, shfl two-min merge ----
#pragma unroll
  for (int p = 0; p < 5; ++p) {
    const int gn = min(cnt[p], Kc[p]);  // gnum >= 1 (seed itself is in pcs)
    const float ed = expdc[p];
    const int lb = off[p];
    double localS = 0.0;
    for (int r0 = 0; r0 < gn; r0 += 64) {
      const int row = r0 + (tid >> 2);
      const int sub = tid & 3;
      float m1 = INFINITY, m2 = INFINITY;
      if (row < gn) {
        const float xi = lx[lb + row], yi = ly[lb + row], zi = lz[lb + row];
        for (int j = sub; j < gn; j += 4) {
          const float d2 = sqdist(xi, yi, zi, lx[lb + j], ly[lb + j], lz[lb + j]);
          if (d2 < m1) { m2 = m1; m1 = d2; }
          else if (d2 < m2) { m2 = d2; }
        }
      }
      // merge (m1,m2) pairs across the 4 sub-lanes (multiset two-min)
#pragma unroll
      for (int d = 1; d <= 2; d <<= 1) {
        const float om1 = __shfl_xor(m1, d);
        const float om2 = __shfl_xor(m2, d);
        const float lo = fminf(m1, om1);
        const float hi = fmaxf(m1, om1);
        m2 = fminf(fminf(m2, om2), hi);
        m1 = lo;
      }
      if (row < gn && sub == 0) {
        const float nn2 = (m2 > 1e37f) ? 0.0f : m2;  // inf (gn==1) -> 0
        const float nnd = (nn2 > 0.0f) ? sqrtf(nn2) : 0.0f;
        const float diff = __fsub_rn(nnd, ed);
        const float clut = __fdiv_rn(__fmul_rn(diff, diff),
                                     __fadd_rn(ed, 1e-12f));
        localS += (double)clut;
      }
    }
#pragma unroll
    for (int o = 32; o > 0; o >>= 1) localS += __shfl_down(localS, o);
    if (lane == 0) wsum[wid] = localS;
    __syncthreads();
    if (tid == 0) {
      const double S = wsum[0] + wsum[1] + wsum[2] + wsum[3];
      atomicAdd(&totS[p], S);
      const float gf = (float)gn;
      const float dd = __fsub_rn(gf, expnf[p]);
      const float imb = __fdiv_rn(__fmul_rn(dd, dd), expnf[p]);
      atomicAdd(&accA[p * 4 + b], (double)imb / (double)gf);
    }
    __syncthreads();  // wsum reused next p
  }
}

// ---------------------------------------------------------------------------
// Kernel 3: loss[b] = (1/5) * sum_p totS[p] * (accA[p][b] / 409)
// ---------------------------------------------------------------------------
__global__ void finalize_kernel(const double* __restrict__ totS,
                                const double* __restrict__ accA,
                                float* __restrict__ out) {
  const int b = threadIdx.x;
  if (b < B_SZ) {
    double acc = 0.0;
    for (int p = 0; p < 5; ++p)
      acc += totS[p] * (accA[p * 4 + b] / (double)SEED_NUM);
    out[b] = (float)(acc / 5.0);
  }
}

extern "C" void kernel_launch(void* const* d_in, const int* in_sizes, int n_in,
                              void* d_out, int out_size, void* d_ws,
                              size_t ws_size, hipStream_t stream) {
  (void)in_sizes; (void)n_in; (void)out_size; (void)ws_size;
  const float* pcs = (const float*)d_in[0];
  float* out = (float*)d_out;

  // ws layout: seeds (B*409*3 f32 = 19632 B, 8-aligned), then 25 doubles.
  float* seeds = (float*)d_ws;
  double* sums = (double*)((char*)d_ws + 19632);

  fps_kernel<<<B_SZ, FPS_THREADS, 0, stream>>>(pcs, seeds, sums);
  group_kernel<<<B_SZ * SEED_NUM, 256, 0, stream>>>(pcs, seeds, sums, sums + 5);
  finalize_kernel<<<1, 64, 0, stream>>>(sums, sums + 5, out);
}